// Round 8
// baseline (98.569 us; speedup 1.0000x reference)
//
#include <hip/hip_runtime.h>

// CNF vector field + exact divergence via bilinear-form trick, MFMA edition.
//   dx  = tanh(tanh([x,t]W1+b1)W2+b2)W3+b3, /2
//   div = 0.5 * d1^T (W2 ∘ (W1[:64]^T W3^T)) d2
// R8: column-split phase 2 across 2 blocks (block = (sample-group, col-half)):
//   512 blocks, 2/CU, half the L2 loads per block -> latency halved, TLP 2x.
//   dx/div combined across halves via fp32 atomicAdd into memset-0 d_out.
// Invariants: 512-thr blocks (1024 spills); bf16 pack layout verified (3.9e-3).

constexpr int HD = 512;
constexpr int DD = 64;
constexpr int SB = 8;
constexpr int NBLK = 2 * 2048 / SB;   // 512 blocks: (sg<256, q<2)

typedef __attribute__((ext_vector_type(8))) short bf16x8;
typedef __attribute__((ext_vector_type(4))) float f32x4;

__device__ inline unsigned short f2bf(float f) {
    union { float f; unsigned u; } v; v.f = f;
    return (unsigned short)((v.u + 0x7fffu + ((v.u >> 16) & 1u)) >> 16);
}
__device__ inline float fast_tanh(float xx) {
    float e = __expf(2.f * xx);
    return 1.f - 2.f / (e + 1.f);
}

// ---------------- pack kernel: Bpack = bf16 fragment-ordered [W2 | G] --------
// chunk c = (mat*32 + t)*16 + kk; lane l: 8 bf16 = B[kk*32+(l>>4)*8+j][t*16+(l&15)]
// (layout verified R5-R7). mat 1 computes G inline.
__global__ __launch_bounds__(64) void cnf_pack_kernel(
    const float* __restrict__ W1, const float* __restrict__ W2,
    const float* __restrict__ W3, unsigned short* __restrict__ Bpack)
{
    __shared__ float w1s[64][33];
    __shared__ float w3s[16][65];
    const int b = blockIdx.x;                 // 0..1023
    const int mat = b >> 9, t = (b >> 4) & 31, kk = b & 15;
    const int l = threadIdx.x;
    const int q = l >> 4, nl = l & 15;
    const int n = t * 16 + nl;
    unsigned short o[8];
    if (mat == 0) {
#pragma unroll
        for (int j = 0; j < 8; ++j) {
            int k = kk * 32 + q * 8 + j;
            o[j] = f2bf(W2[k * HD + n]);
        }
    } else {
        for (int e = l; e < 64 * 32; e += 64) {
            int i = e >> 5, kl = e & 31;
            w1s[i][kl] = W1[i * HD + kk * 32 + kl];
        }
        for (int e = l; e < 16 * 64; e += 64) {
            int nn = e >> 6, i = e & 63;
            w3s[nn][i] = W3[(t * 16 + nn) * DD + i];
        }
        __syncthreads();
#pragma unroll
        for (int j = 0; j < 8; ++j) {
            int kl = q * 8 + j;
            float m = 0.f;
#pragma unroll 8
            for (int i = 0; i < 64; ++i) m += w1s[i][kl] * w3s[nl][i];
            o[j] = f2bf(W2[(kk * 32 + kl) * HD + n] * m);
        }
    }
    uint4 pk;
    pk.x = (unsigned)o[0] | ((unsigned)o[1] << 16);
    pk.y = (unsigned)o[2] | ((unsigned)o[3] << 16);
    pk.z = (unsigned)o[4] | ((unsigned)o[5] << 16);
    pk.w = (unsigned)o[6] | ((unsigned)o[7] << 16);
    reinterpret_cast<uint4*>(Bpack)[b * 64 + l] = pk;
}

// ---------------- fused MLP + divergence, 512 thr, col-half per block --------
__global__ __launch_bounds__(512, 4) void cnf_fused_kernel(
    const float* __restrict__ tptr, const float* __restrict__ x,
    const float* __restrict__ W1, const float* __restrict__ b1,
    const float* __restrict__ b2v, const float* __restrict__ W3,
    const float* __restrict__ b3, const unsigned short* __restrict__ Bpack,
    float* __restrict__ out)
{
    __shared__ float4 xsv[65 * 2];             // [i][s0-3],[i][s4-7]
    __shared__ unsigned short A_lds[16][520];  // bf16 A; reused as opart (fp32 8x512)
    __shared__ float4 h2v[256 * 2];            // [ml][quad]  (own half's m only)
    __shared__ float4 divred[8][2];
    __shared__ float sm_b2[256];

    const int tid  = threadIdx.x;
    const int sg   = blockIdx.x >> 1;          // sample group
    const int q    = blockIdx.x & 1;           // column half
    const int s0   = sg * SB;
    const int wave = tid >> 6, lane = tid & 63;

    // ---- phase 0: stage x rows (drop col 64, append t) + b2 half ----
    {
        const float tval = tptr[0];
        for (int e = tid; e < SB * 65; e += 512) {
            int s = e / 65, i = e % 65;
            reinterpret_cast<float*>(xsv)[i * SB + s] =
                (i == DD) ? tval : x[(s0 + s) * 65 + i];
        }
        if (tid < 256) sm_b2[tid] = b2v[q * 256 + tid];
    }
    __syncthreads();

    // ---- phase 1: layer 1 fp32; thread = unit u, all 8 samples ----
    {
        const int u = tid;
        const float bb = b1[u];
        float2 a0 = {bb, bb}, a1 = {bb, bb}, a2 = {bb, bb}, a3 = {bb, bb};
        for (int ib = 0; ib < 64; ib += 8) {
            float w[8];
#pragma unroll
            for (int qq = 0; qq < 8; ++qq) w[qq] = W1[(ib + qq) * HD + u];
#pragma unroll
            for (int qq = 0; qq < 8; ++qq) {
                float4 p = xsv[2 * (ib + qq)], r = xsv[2 * (ib + qq) + 1];
                a0.x += p.x * w[qq]; a0.y += p.y * w[qq];
                a1.x += p.z * w[qq]; a1.y += p.w * w[qq];
                a2.x += r.x * w[qq]; a2.y += r.y * w[qq];
                a3.x += r.z * w[qq]; a3.y += r.w * w[qq];
            }
        }
        {
            float w = W1[64 * HD + u];
            float4 p = xsv[128], r = xsv[129];
            a0.x += p.x * w; a0.y += p.y * w;
            a1.x += p.z * w; a1.y += p.w * w;
            a2.x += r.x * w; a2.y += r.y * w;
            a3.x += r.z * w; a3.y += r.w * w;
        }
        float h[8] = {fast_tanh(a0.x), fast_tanh(a0.y), fast_tanh(a1.x), fast_tanh(a1.y),
                      fast_tanh(a2.x), fast_tanh(a2.y), fast_tanh(a3.x), fast_tanh(a3.y)};
#pragma unroll
        for (int s = 0; s < 8; ++s) {
            A_lds[s][u]     = f2bf(h[s]);
            A_lds[8 + s][u] = f2bf(1.f - h[s] * h[s]);
        }
    }
    __syncthreads();

    // ---- phase 2: MFMA. wave w: cols [q*256+w*32, +32) of BOTH W2 and G ----
    f32x4 cw[2], cg[2];
#pragma unroll
    for (int i = 0; i < 2; ++i) { cw[i] = (f32x4){0,0,0,0}; cg[i] = (f32x4){0,0,0,0}; }
    {
        const unsigned short* arow = &A_lds[lane & 15][0];
        const int aoff = (lane >> 4) * 8;   // ushorts
        const int t0 = q * 16 + wave * 2;   // first 16-col tile of this wave
        const bf16x8* bw = reinterpret_cast<const bf16x8*>(Bpack)
                         + (size_t)(t0 * 16) * 64 + lane;   // tile stride = 1024 frags
        const bf16x8* bg = bw + 32768;      // mat 1 offset = 32*16*64 frags

        bf16x8 pA[8], pB[8];                // ping-pong: 2 kk-steps, 8 loads each
        auto loadSB = [&](bf16x8* d, int kk) {
#pragma unroll
            for (int v = 0; v < 2; ++v) {   // kk, kk+1
#pragma unroll
                for (int i = 0; i < 2; ++i) {
                    d[v * 4 + i]     = bw[(kk + v) * 64 + i * 1024];
                    d[v * 4 + 2 + i] = bg[(kk + v) * 64 + i * 1024];
                }
            }
        };
        auto mfmaSB = [&](const bf16x8* d, int kk) {
#pragma unroll
            for (int v = 0; v < 2; ++v) {
                bf16x8 af = *reinterpret_cast<const bf16x8*>(arow + (kk + v) * 32 + aoff);
#pragma unroll
                for (int i = 0; i < 2; ++i)
                    cw[i] = __builtin_amdgcn_mfma_f32_16x16x32_bf16(af, d[v * 4 + i], cw[i], 0, 0, 0);
#pragma unroll
                for (int i = 0; i < 2; ++i)
                    cg[i] = __builtin_amdgcn_mfma_f32_16x16x32_bf16(af, d[v * 4 + 2 + i], cg[i], 0, 0, 0);
            }
        };

        loadSB(pA, 0);
#pragma unroll
        for (int kb = 0; kb < 8; ++kb) {
            bf16x8* cur = (kb & 1) ? pB : pA;
            bf16x8* nxt = (kb & 1) ? pA : pB;
            if (kb < 7) loadSB(nxt, (kb + 1) * 2);
            mfmaSB(cur, kb * 2);
        }
    }

    // ---- epilogue: h2 (lanes 0-31 rows) + div partials (lanes 32-63 rows) ----
    {
        const int qd = lane >> 4;                 // row-quad 0..3
        const int src = (lane >= 32) ? lane - 32 : lane;
        float4 dp = {0.f, 0.f, 0.f, 0.f};
#pragma unroll
        for (int i = 0; i < 2; ++i) {
            const int ml = wave * 32 + i * 16 + (lane & 15);   // local m (0..255)
            const float bb = sm_b2[ml];
            float4 hv;
            hv.x = fast_tanh(cw[i][0] + bb);
            hv.y = fast_tanh(cw[i][1] + bb);
            hv.z = fast_tanh(cw[i][2] + bb);
            hv.w = fast_tanh(cw[i][3] + bb);
            if (lane < 32) h2v[2 * ml + qd] = hv;  // rows 0-7 = h-samples
            float h0 = __shfl(hv.x, src), h1s = __shfl(hv.y, src);
            float h2s = __shfl(hv.z, src), h3s = __shfl(hv.w, src);
            dp.x += cg[i][0] * (1.f - h0 * h0);
            dp.y += cg[i][1] * (1.f - h1s * h1s);
            dp.z += cg[i][2] * (1.f - h2s * h2s);
            dp.w += cg[i][3] * (1.f - h3s * h3s);
        }
        if (lane >= 32) {
#pragma unroll
            for (int off = 8; off > 0; off >>= 1) {
                dp.x += __shfl_down(dp.x, off, 16);
                dp.y += __shfl_down(dp.y, off, 16);
                dp.z += __shfl_down(dp.z, off, 16);
                dp.w += __shfl_down(dp.w, off, 16);
            }
            if ((lane & 15) == 0) divred[wave][qd - 2] = dp;
        }
    }
    __syncthreads();   // h2v + divred complete; A_lds free

    float* opart = reinterpret_cast<float*>(A_lds);   // 8 x 512 fp32

    // ---- phase 4: layer 3 partial over own 256 m's; part = wave, k = lane ----
    {
        const int k = lane, part = wave;
        float o[8];
#pragma unroll
        for (int qq = 0; qq < 8; ++qq) o[qq] = 0.f;
        const int mb = part * 32;                       // local m base
        for (int mm = 0; mm < 32; mm += 4) {
            float w[4];
#pragma unroll
            for (int j = 0; j < 4; ++j)
                w[j] = W3[(q * 256 + mb + mm + j) * DD + k];
#pragma unroll
            for (int j = 0; j < 4; ++j) {
                const int ml = mb + mm + j;
                float4 ha = h2v[2 * ml], hb = h2v[2 * ml + 1];
                o[0] += ha.x * w[j]; o[1] += ha.y * w[j];
                o[2] += ha.z * w[j]; o[3] += ha.w * w[j];
                o[4] += hb.x * w[j]; o[5] += hb.y * w[j];
                o[6] += hb.z * w[j]; o[7] += hb.w * w[j];
            }
        }
#pragma unroll
        for (int qq = 0; qq < 8; ++qq) opart[part * 512 + qq * 64 + k] = o[qq];
    }
    __syncthreads();

    // ---- outputs: atomic combine across the two column-halves ----
    {
        const int s = tid >> 6, k = tid & 63;
        float sum = (q == 0) ? b3[k] : 0.f;
#pragma unroll
        for (int p = 0; p < 8; ++p) sum += opart[p * 512 + s * 64 + k];
        atomicAdd(&out[(s0 + s) * 65 + k], 0.5f * sum);
    }
    if (tid < 8) {
        const int qq = tid >> 2, r = tid & 3;
        float ds = 0.f;
#pragma unroll
        for (int w = 0; w < 8; ++w)
            ds += reinterpret_cast<const float*>(&divred[w][qq])[r];
        atomicAdd(&out[(s0 + tid) * 65 + DD], 0.5f * ds);
    }
}

extern "C" void kernel_launch(void* const* d_in, const int* in_sizes, int n_in,
                              void* d_out, int out_size, void* d_ws, size_t ws_size,
                              hipStream_t stream) {
    const float* t  = (const float*)d_in[0];
    const float* x  = (const float*)d_in[1];
    const float* W1 = (const float*)d_in[2];
    const float* b1 = (const float*)d_in[3];
    const float* W2 = (const float*)d_in[4];
    const float* b2 = (const float*)d_in[5];
    const float* W3 = (const float*)d_in[6];
    const float* b3 = (const float*)d_in[7];
    float* out = (float*)d_out;
    unsigned short* Bpack = (unsigned short*)d_ws;   // 2*512*512 bf16 = 1 MB

    hipMemsetAsync(out, 0, (size_t)out_size * sizeof(float), stream);
    cnf_pack_kernel<<<1024, 64, 0, stream>>>(W1, W2, W3, Bpack);
    cnf_fused_kernel<<<NBLK, 512, 0, stream>>>(t, x, W1, b1, b2, W3, b3, Bpack, out);
}